// Round 6
// baseline (10.178 us; speedup 1.0000x reference)
//
#include <hip/hip_runtime.h>
#include <math.h>

__device__ __forceinline__ float sigm(float x) { return 1.0f / (1.0f + __expf(-x)); }

// Encoder GRU single step with h0 = 0, input-size 1, hidden 4.
__device__ __forceinline__ void enc_step(float xb, const float* __restrict__ Wih,
                                         const float* __restrict__ bih,
                                         const float* __restrict__ bhh, float h[4]) {
#pragma unroll
    for (int j = 0; j < 4; ++j) {
        float ir = fmaf(xb, Wih[j],     bih[j])     + bhh[j];
        float iz = fmaf(xb, Wih[4 + j], bih[4 + j]) + bhh[4 + j];
        float in_ = fmaf(xb, Wih[8 + j], bih[8 + j]);
        float hn  = bhh[8 + j];
        float r = sigm(ir);
        float z = sigm(iz);
        float n = tanhf(fmaf(r, hn, in_));
        h[j] = (1.0f - z) * n;
    }
}

// Single dispatch, 32 blocks x 1024 threads. Last-arriver pattern (R4) +
// full register prefetch: all global loads (x, fc1 row slice, fc2 col slice)
// are issued BEFORE the encoder + barrier, so L2 latency hides under compute.
// counter never reset: 32 consecutive olds hit each residue mod 32 exactly
// once regardless of the poisoned start; exactly one tail block per call.
__global__ __launch_bounds__(1024) void fused(const float* __restrict__ x,
                                              const float* __restrict__ eWih,
                                              const float* __restrict__ ebih,
                                              const float* __restrict__ ebhh,
                                              const float* __restrict__ fc1W,
                                              const float* __restrict__ fc1b,
                                              const float* __restrict__ fc2W,
                                              const float* __restrict__ fc2b,
                                              const float* __restrict__ dWih,
                                              const float* __restrict__ dWhh,
                                              const float* __restrict__ dbih,
                                              const float* __restrict__ dbhh,
                                              float* __restrict__ partial,   // [32][256]
                                              unsigned* __restrict__ counter,
                                              float* __restrict__ out) {
    __shared__ float stacked[1000];
    __shared__ float hid16[16];
    __shared__ float psum[1024];
    __shared__ unsigned oldc;
    const int t = threadIdx.x;
    const int wave = t >> 6, lane = t & 63;
    const int b = blockIdx.x;
    const int j = b * 16 + wave;                    // fc1 row for this wave

    // ---- prefetch everything this thread will need from global ----
    const float4 zero4 = make_float4(0.f, 0.f, 0.f, 0.f);
    const float4* w4 = (const float4*)(fc1W + j * 1000);
    float4 wreg[4];
#pragma unroll
    for (int q = 0; q < 4; ++q) {
        const int k = lane + q * 64;
        wreg[q] = (k < 250) ? w4[k] : zero4;        // 250 float4s per row
    }
    float4 w2reg[4];
    if (t < 250) {
        const float4* w2 = (const float4*)(fc2W + t * 512 + b * 16);
#pragma unroll
        for (int o = 0; o < 4; ++o) w2reg[o] = w2[o];
    }
    const float xv   = (t < 250) ? x[t] : 0.0f;
    const float b1   = fc1b[j];

    // ---- encoder (redundant per block) into LDS; overlaps prefetch latency ----
    if (t < 250) {
        float h[4];
        enc_step(xv, eWih, ebih, ebhh, h);
        ((float4*)stacked)[t] = make_float4(h[0], h[1], h[2], h[3]);
    }
    __syncthreads();

    // ---- fc1: wave w computes row j; weights already in registers ----
    const float4* s4 = (const float4*)stacked;     // 250 float4s
    float s = 0.0f;
#pragma unroll
    for (int q = 0; q < 4; ++q) {
        const int k = lane + q * 64;
        if (k < 250) {
            const float4 a = s4[k], w = wreg[q];
            s = fmaf(a.x, w.x, s);
            s = fmaf(a.y, w.y, s);
            s = fmaf(a.z, w.z, s);
            s = fmaf(a.w, w.w, s);
        }
    }
#pragma unroll
    for (int m = 32; m >= 1; m >>= 1) s += __shfl_xor(s, m, 64);
    if (lane == 0) hid16[wave] = fmaxf(s + b1, 0.0f);
    __syncthreads();

    // ---- partial fc2: thread t<250 -> output i=t, k in [16b, 16b+16) ----
    if (t < 250) {
        float p = 0.0f;
#pragma unroll
        for (int o = 0; o < 4; ++o) {
            const float4 w = w2reg[o];
            p = fmaf(w.x, hid16[o * 4 + 0],
                fmaf(w.y, hid16[o * 4 + 1],
                fmaf(w.z, hid16[o * 4 + 2],
                fmaf(w.w, hid16[o * 4 + 3], p))));
        }
        __hip_atomic_store(&partial[b * 256 + t], p,
                           __ATOMIC_RELAXED, __HIP_MEMORY_SCOPE_AGENT);
    }
    asm volatile("s_waitcnt vmcnt(0)" ::: "memory");  // own store at coherent point
    __syncthreads();                                   // whole block drained

    if (t == 0)
        oldc = __hip_atomic_fetch_add(counter, 1u,
                                      __ATOMIC_RELAXED, __HIP_MEMORY_SCOPE_AGENT);
    __syncthreads();
    if ((oldc & 31u) != 31u) return;   // not the last arriver

    // ---- tail (exactly one block per call): 4-way parallel reduce + decoder ----
    const int qq = t >> 8;       // 0..3
    const int i  = t & 255;      // 0..255
    if (i < 250) {
        const float bias = (qq == 0) ? fc2b[i] : 0.0f;   // issue early, overlaps
        float a = 0.0f;
#pragma unroll
        for (int bb = qq * 8; bb < qq * 8 + 8; ++bb) {
            a += __hip_atomic_load(&partial[bb * 256 + i],
                                   __ATOMIC_RELAXED, __HIP_MEMORY_SCOPE_AGENT);
        }
        psum[qq * 256 + i] = a + bias;
    }
    __syncthreads();
    if (qq == 0 && i < 250) {
        const float hn_i = (psum[i] + psum[256 + i]) + (psum[512 + i] + psum[768 + i]);
        // decoder GRU step; encoder y for this i is still in LDS
        const float y0 = stacked[i * 4 + 0], y1 = stacked[i * 4 + 1];
        const float y2 = stacked[i * 4 + 2], y3 = stacked[i * 4 + 3];
        float gi[3];
#pragma unroll
        for (int g = 0; g < 3; ++g) {
            gi[g] = fmaf(y0, dWih[g * 4 + 0],
                    fmaf(y1, dWih[g * 4 + 1],
                    fmaf(y2, dWih[g * 4 + 2],
                    fmaf(y3, dWih[g * 4 + 3], dbih[g]))));
        }
        const float gh0 = fmaf(hn_i, dWhh[0], dbhh[0]);
        const float gh1 = fmaf(hn_i, dWhh[1], dbhh[1]);
        const float gh2 = fmaf(hn_i, dWhh[2], dbhh[2]);
        const float r = sigm(gi[0] + gh0);
        const float z = sigm(gi[1] + gh1);
        const float n = tanhf(fmaf(r, gh2, gi[2]));
        out[i] = fmaf(z, hn_i, (1.0f - z) * n);
    }
}

extern "C" void kernel_launch(void* const* d_in, const int* in_sizes, int n_in,
                              void* d_out, int out_size, void* d_ws, size_t ws_size,
                              hipStream_t stream) {
    const float* x     = (const float*)d_in[0];
    const float* eWih  = (const float*)d_in[1];
    // d_in[2] = enc_Whh — unused (h0 == 0 makes the Whh term vanish)
    const float* ebih  = (const float*)d_in[3];
    const float* ebhh  = (const float*)d_in[4];
    const float* fc1W  = (const float*)d_in[5];
    const float* fc1b  = (const float*)d_in[6];
    const float* fc2W  = (const float*)d_in[7];
    const float* fc2b  = (const float*)d_in[8];
    const float* dWih  = (const float*)d_in[9];
    const float* dWhh  = (const float*)d_in[10];
    const float* dbih  = (const float*)d_in[11];
    const float* dbhh  = (const float*)d_in[12];
    float* out = (float*)d_out;

    float*    partial = (float*)d_ws;                        // 32*256 floats = 32 KB
    unsigned* counter = (unsigned*)((char*)d_ws + 32 * 256 * 4);

    fused<<<32, 1024, 0, stream>>>(x, eWih, ebih, ebhh, fc1W, fc1b, fc2W, fc2b,
                                   dWih, dWhh, dbih, dbhh, partial, counter, out);
}